// Round 1
// 168.339 us; speedup vs baseline: 1.0512x; 1.0512x over previous
//
#include <hip/hip_runtime.h>

// Hierarchical sparse attention (binary tree), MI355X gfx950.
// B=4, S=4096, H=8, D=64, f32.
//
// v2 restructure:
//  - Only the 126 high tree nodes per (b,h) (levels 6..11) are materialized
//    in global memory (4 MB total instead of 67 MB for the full tree).
//  - attn is chunk-based: one block per (bh, 64-query chunk) rebuilds the
//    in-chunk tree levels 1..5 in LDS from the k/v leaves it reads anyway;
//    the <=6 path nodes for levels 6..11 are block-uniform and staged once.
//  - Removes ~130 MB of tree HBM round-trip and converts the old attn's
//    scattered 256B tree reads (2.6 TB/s effective, 29% occupancy) into
//    LDS hits with fully coalesced global traffic.

#define S 4096
#define H 8
#define D 64
#define B 4
#define NBH 32
#define NHI 126           // per-bh high nodes: 64+32+16+8+4+2 (levels 6..11)
#define SCALE 0.125f

__device__ inline float red16(float x) {
    x += __shfl_xor(x, 1);
    x += __shfl_xor(x, 2);
    x += __shfl_xor(x, 4);
    x += __shfl_xor(x, 8);
    return x;
}

__device__ inline float dot4(const float4 a, const float4 b) {
    return a.x * b.x + a.y * b.y + a.z * b.z + a.w * b.w;
}

// parent(k,v) from two children: softmax-weighted merge (16-lane reduce).
__device__ inline void combine(const float4 k0, const float4 k1,
                               const float4 v0, const float4 v1,
                               float4& kp, float4& vp) {
    kp.x = 0.5f * (k0.x + k1.x);
    kp.y = 0.5f * (k0.y + k1.y);
    kp.z = 0.5f * (k0.z + k1.z);
    kp.w = 0.5f * (k0.w + k1.w);
    float pss = red16(dot4(kp, kp)) * SCALE;
    float p0  = red16(dot4(kp, k0)) * SCALE;
    float p1  = red16(dot4(kp, k1)) * SCALE;
    float m  = fmaxf(pss, fmaxf(p0, p1));
    float es = __expf(pss - m), e0 = __expf(p0 - m), e1 = __expf(p1 - m);
    float inv = 1.0f / (es + e0 + e1 + 1e-9f);
    float h = 0.5f * es;
    vp.x = ((h + e0) * v0.x + (h + e1) * v1.x) * inv;
    vp.y = ((h + e0) * v0.y + (h + e1) * v1.y) * inv;
    vp.z = ((h + e0) * v0.z + (h + e1) * v1.z) * inv;
    vp.w = ((h + e0) * v0.w + (h + e1) * v1.w) * inv;
}

// K1: per (bh, 64-leaf chunk) build levels 1..6 in LDS; write ONLY the
// chunk root (level-6 node) to the global hi-tree at index c.
__global__ __launch_bounds__(256) void chunk_root(
    const float* __restrict__ k, const float* __restrict__ v,
    float* __restrict__ khi, float* __restrict__ vhi)
{
    __shared__ float lkA[32 * 64], lvA[32 * 64];
    __shared__ float lkB[16 * 64], lvB[16 * 64];
    const int t = threadIdx.x;
    const int sub = t & 15;
    const int pg = t >> 4;
    const int blk = blockIdx.x;
    const int c = blk & 63;
    const int bh = blk >> 6;
    const int b = bh >> 3, h = bh & 7;

    // level 1: 32 parents from global leaves
#pragma unroll
    for (int r = 0; r < 2; ++r) {
        int j = pg + r * 16;
        int s0 = c * 64 + 2 * j;
        size_t a0 = ((((size_t)b * S + s0) * H + h) * D) + sub * 4;
        float4 k0 = *(const float4*)(k + a0);
        float4 k1 = *(const float4*)(k + a0 + H * D);
        float4 v0 = *(const float4*)(v + a0);
        float4 v1 = *(const float4*)(v + a0 + H * D);
        float4 kp, vp;
        combine(k0, k1, v0, v1, kp, vp);
        *(float4*)(lkA + j * 64 + sub * 4) = kp;
        *(float4*)(lvA + j * 64 + sub * 4) = vp;
    }
    __syncthreads();

    float *sk = lkA, *sv = lvA, *dk = lkB, *dv = lvB;
#pragma unroll
    for (int l = 2; l <= 6; ++l) {
        int np = 64 >> l;            // 16,8,4,2,1
        if (pg < np) {
            int j = pg;
            float4 k0 = *(const float4*)(sk + (2 * j) * 64 + sub * 4);
            float4 k1 = *(const float4*)(sk + (2 * j + 1) * 64 + sub * 4);
            float4 v0 = *(const float4*)(sv + (2 * j) * 64 + sub * 4);
            float4 v1 = *(const float4*)(sv + (2 * j + 1) * 64 + sub * 4);
            float4 kp, vp;
            combine(k0, k1, v0, v1, kp, vp);
            if (l < 6) {
                *(float4*)(dk + j * 64 + sub * 4) = kp;
                *(float4*)(dv + j * 64 + sub * 4) = vp;
            } else {
                size_t g = ((size_t)bh * NHI + c) * 64 + sub * 4;
                *(float4*)(khi + g) = kp;
                *(float4*)(vhi + g) = vp;
            }
        }
        __syncthreads();
        float* tp;
        tp = sk; sk = dk; dk = tp;
        tp = sv; sv = dv; dv = tp;
    }
}

// K2: per bh, build levels 7..11 from the 64 level-6 roots.
// hi layout per bh: [0,64)=l6, [64,96)=l7, [96,112)=l8, [112,120)=l9,
//                   [120,124)=l10, [124,126)=l11.
__global__ __launch_bounds__(256) void build_hi(
    float* __restrict__ khi, float* __restrict__ vhi)
{
    __shared__ float lk[NHI * 64], lv[NHI * 64];   // 31.5 KB each
    const int t = threadIdx.x;
    const int sub = t & 15;
    const int pg = t >> 4;
    const int bh = blockIdx.x;
    size_t base = (size_t)bh * NHI * 64;

    // load level-6 row (64 nodes = 1024 float4 slots)
    for (int i = t; i < 1024; i += 256) {
        *(float4*)(lk + i * 4) = *(const float4*)(khi + base + i * 4);
        *(float4*)(lv + i * 4) = *(const float4*)(vhi + base + i * 4);
    }
    __syncthreads();

    int srcOff = 0, dstOff = 64, np = 32;
#pragma unroll
    for (int l = 7; l <= 11; ++l) {
        for (int j = pg; j < np; j += 16) {
            float4 k0 = *(const float4*)(lk + (srcOff + 2 * j) * 64 + sub * 4);
            float4 k1 = *(const float4*)(lk + (srcOff + 2 * j + 1) * 64 + sub * 4);
            float4 v0 = *(const float4*)(lv + (srcOff + 2 * j) * 64 + sub * 4);
            float4 v1 = *(const float4*)(lv + (srcOff + 2 * j + 1) * 64 + sub * 4);
            float4 kp, vp;
            combine(k0, k1, v0, v1, kp, vp);
            *(float4*)(lk + (dstOff + j) * 64 + sub * 4) = kp;
            *(float4*)(lv + (dstOff + j) * 64 + sub * 4) = vp;
            *(float4*)(khi + base + (size_t)(dstOff + j) * 64 + sub * 4) = kp;
            *(float4*)(vhi + base + (size_t)(dstOff + j) * 64 + sub * 4) = vp;
        }
        __syncthreads();
        srcOff = dstOff; dstOff += np; np >>= 1;
    }
}

// K3: chunk-based attention. Block = (bh, chunk of 64 queries).
// Rebuilds in-chunk tree levels 1..5 in LDS; path nodes 6..11 staged once.
__global__ __launch_bounds__(256) void attn_chunk(
    const float* __restrict__ q, const float* __restrict__ k,
    const float* __restrict__ v,
    const float* __restrict__ khi, const float* __restrict__ vhi,
    float* __restrict__ out)
{
    __shared__ float tk[62 * 64], tv[62 * 64];   // levels 1..5: 15.5 KB each
    __shared__ float pk[6 * 64], pv[6 * 64];     // path nodes l6..11: 1.5 KB each
    const int t = threadIdx.x;
    const int sub = t & 15;
    const int pg = t >> 4;
    const int blk = blockIdx.x;
    const int c = blk & 63;
    const int bh = blk >> 6;
    const int b = bh >> 3, h = bh & 7;

    // stage path nodes for levels 6..11 (block-uniform); groups 0..5: k, 6..11: v
    if (pg < 12) {
        int lh = (pg >= 6) ? pg - 6 : pg;        // level - 6
        if ((c >> lh) & 1) {
            int off = 128 - (128 >> lh);         // 0,64,96,112,120,124
            int node = off + ((c >> lh) ^ 1);
            size_t a = ((size_t)bh * NHI + node) * 64 + sub * 4;
            if (pg < 6) *(float4*)(pk + lh * 64 + sub * 4) = *(const float4*)(khi + a);
            else        *(float4*)(pv + lh * 64 + sub * 4) = *(const float4*)(vhi + a);
        }
    }

    // in-chunk tree level 1: nodes 0..31
#pragma unroll
    for (int r = 0; r < 2; ++r) {
        int j = pg + r * 16;
        int s0 = c * 64 + 2 * j;
        size_t a0 = ((((size_t)b * S + s0) * H + h) * D) + sub * 4;
        float4 k0 = *(const float4*)(k + a0);
        float4 k1 = *(const float4*)(k + a0 + H * D);
        float4 v0 = *(const float4*)(v + a0);
        float4 v1 = *(const float4*)(v + a0 + H * D);
        float4 kp, vp;
        combine(k0, k1, v0, v1, kp, vp);
        *(float4*)(tk + j * 64 + sub * 4) = kp;
        *(float4*)(tv + j * 64 + sub * 4) = vp;
    }
    __syncthreads();

    // levels 2..5: nodes 32..47, 48..55, 56..59, 60..61
    {
        int srcOff = 0, dstOff = 32, np = 16;
#pragma unroll
        for (int l = 2; l <= 5; ++l) {
            if (pg < np) {
                int j = pg;
                float4 k0 = *(const float4*)(tk + (srcOff + 2 * j) * 64 + sub * 4);
                float4 k1 = *(const float4*)(tk + (srcOff + 2 * j + 1) * 64 + sub * 4);
                float4 v0 = *(const float4*)(tv + (srcOff + 2 * j) * 64 + sub * 4);
                float4 v1 = *(const float4*)(tv + (srcOff + 2 * j + 1) * 64 + sub * 4);
                float4 kp, vp;
                combine(k0, k1, v0, v1, kp, vp);
                *(float4*)(tk + (dstOff + j) * 64 + sub * 4) = kp;
                *(float4*)(tv + (dstOff + j) * 64 + sub * 4) = vp;
            }
            __syncthreads();
            srcOff = dstOff; dstOff += np; np >>= 1;
        }
    }

    // scoring: each 16-lane group handles queries sl = pg + 16r
#pragma unroll 1
    for (int r = 0; r < 4; ++r) {
        int sl = pg + r * 16;
        int s = c * 64 + sl;
        size_t qa = ((((size_t)b * S + s) * H + h) * D) + sub * 4;
        float4 q4 = *(const float4*)(q + qa);
        float4 k4 = *(const float4*)(k + qa);
        float4 v4 = *(const float4*)(v + qa);

        float ss = red16(dot4(q4, k4)) * SCALE;

        float sc[12];
        float4 vc0 = v4;                 // dummy init (guarded by odd)
        const bool odd = (s & 1) != 0;
        if (odd) {
            float4 kc0 = *(const float4*)(k + qa - H * D);
            vc0 = *(const float4*)(v + qa - H * D);
            sc[0] = red16(dot4(q4, kc0)) * SCALE;
        } else {
            sc[0] = -1e38f;
        }
#pragma unroll
        for (int l = 1; l <= 5; ++l) {
            if ((s >> l) & 1) {
                int base = 64 - (64 >> (l - 1));          // 0,32,48,56,60
                int loc = base + (((s >> l) ^ 1) - (c << (6 - l)));
                float4 kc = *(const float4*)(tk + loc * 64 + sub * 4);
                sc[l] = red16(dot4(q4, kc)) * SCALE;
            } else sc[l] = -1e38f;
        }
#pragma unroll
        for (int l = 6; l <= 11; ++l) {
            if ((c >> (l - 6)) & 1) {                     // == bit l of s
                float4 kc = *(const float4*)(pk + (l - 6) * 64 + sub * 4);
                sc[l] = red16(dot4(q4, kc)) * SCALE;
            } else sc[l] = -1e38f;
        }

        float m = ss;
#pragma unroll
        for (int l = 0; l < 12; ++l) m = fmaxf(m, sc[l]);

        float es = __expf(ss - m);
        float denom = es;
        float4 acc;
        acc.x = es * v4.x; acc.y = es * v4.y; acc.z = es * v4.z; acc.w = es * v4.w;

        if (odd) {
            float e = __expf(sc[0] - m);
            denom += e;
            acc.x += e * vc0.x; acc.y += e * vc0.y;
            acc.z += e * vc0.z; acc.w += e * vc0.w;
        }
#pragma unroll
        for (int l = 1; l <= 5; ++l) {
            if ((s >> l) & 1) {
                int base = 64 - (64 >> (l - 1));
                int loc = base + (((s >> l) ^ 1) - (c << (6 - l)));
                float4 vc = *(const float4*)(tv + loc * 64 + sub * 4);
                float e = __expf(sc[l] - m);
                denom += e;
                acc.x += e * vc.x; acc.y += e * vc.y;
                acc.z += e * vc.z; acc.w += e * vc.w;
            }
        }
#pragma unroll
        for (int l = 6; l <= 11; ++l) {
            if ((c >> (l - 6)) & 1) {
                float4 vc = *(const float4*)(pv + (l - 6) * 64 + sub * 4);
                float e = __expf(sc[l] - m);
                denom += e;
                acc.x += e * vc.x; acc.y += e * vc.y;
                acc.z += e * vc.z; acc.w += e * vc.w;
            }
        }
        float inv = 1.0f / denom;
        float4 o;
        o.x = acc.x * inv; o.y = acc.y * inv;
        o.z = acc.z * inv; o.w = acc.w * inv;
        *(float4*)(out + qa) = o;
    }
}

extern "C" void kernel_launch(void* const* d_in, const int* in_sizes, int n_in,
                              void* d_out, int out_size, void* d_ws, size_t ws_size,
                              hipStream_t stream) {
    const float* q = (const float*)d_in[0];
    const float* k = (const float*)d_in[1];
    const float* v = (const float*)d_in[2];
    float* outp = (float*)d_out;
    float* khi = (float*)d_ws;                      // 32*126*64 f32 ~= 2 MB
    float* vhi = khi + (size_t)NBH * NHI * D;

    hipLaunchKernelGGL(chunk_root, dim3(NBH * 64), dim3(256), 0, stream,
                       k, v, khi, vhi);
    hipLaunchKernelGGL(build_hi, dim3(NBH), dim3(256), 0, stream, khi, vhi);
    hipLaunchKernelGGL(attn_chunk, dim3(NBH * 64), dim3(256), 0, stream,
                       q, k, v, khi, vhi, outp);
}